// Round 1
// baseline (214.084 us; speedup 1.0000x reference)
//
#include <hip/hip_runtime.h>
#include <math.h>

#define WIN 11
#define TILE 32
#define IN_TILE (TILE + WIN - 1)  // 42
#define NTHREADS 256

struct GaussW { float g[WIN]; };

__global__ __launch_bounds__(NTHREADS) void ssim_fused_kernel(
    const float* __restrict__ X, const float* __restrict__ Y,
    double* __restrict__ accum, GaussW gw,
    int H, int W, int OH, int OW, int tiles_h, int tiles_w)
{
    __shared__ float sX[IN_TILE][IN_TILE];
    __shared__ float sY[IN_TILE][IN_TILE];
    __shared__ float V[5][TILE][IN_TILE];
    __shared__ float wsum[NTHREADS / 64];

    const int tiles_per_img = tiles_h * tiles_w;
    const int img = blockIdx.x / tiles_per_img;
    const int t   = blockIdx.x % tiles_per_img;
    const int th  = t / tiles_w;
    const int tw  = t % tiles_w;
    const int row0 = th * TILE;
    const int col0 = tw * TILE;

    const float* __restrict__ Xb = X + (size_t)img * H * W;
    const float* __restrict__ Yb = Y + (size_t)img * H * W;

    const int tid = threadIdx.x;

    // ---- Stage 0: global -> LDS (clamped at image edges; clamped values
    // only feed positions whose outputs are masked off later) ----
    for (int i = tid; i < IN_TILE * IN_TILE; i += NTHREADS) {
        int r = i / IN_TILE, c = i % IN_TILE;
        int gr = row0 + r; if (gr > H - 1) gr = H - 1;
        int gc = col0 + c; if (gc > W - 1) gc = W - 1;
        size_t off = (size_t)gr * W + gc;
        sX[r][c] = Xb[off];
        sY[r][c] = Yb[off];
    }
    __syncthreads();

    // ---- Stage 1: vertical 11-tap blur of 5 channels into LDS ----
    for (int i = tid; i < TILE * IN_TILE; i += NTHREADS) {
        int r = i / IN_TILE, c = i % IN_TILE;
        float m1 = 0.f, m2 = 0.f, xx = 0.f, yy = 0.f, xy = 0.f;
        #pragma unroll
        for (int k = 0; k < WIN; ++k) {
            float g = gw.g[k];
            float x = sX[r + k][c];
            float y = sY[r + k][c];
            m1 = fmaf(g, x, m1);
            m2 = fmaf(g, y, m2);
            xx = fmaf(g * x, x, xx);
            yy = fmaf(g * y, y, yy);
            xy = fmaf(g * x, y, xy);
        }
        V[0][r][c] = m1;
        V[1][r][c] = m2;
        V[2][r][c] = xx;
        V[3][r][c] = yy;
        V[4][r][c] = xy;
    }
    __syncthreads();

    // ---- Stage 2: horizontal 11-tap blur + SSIM epilogue ----
    const float C1 = 0.0001f;  // (K1*data_range)^2
    const float C2 = 0.0009f;  // (K2*data_range)^2
    float sum = 0.f;
    for (int i = tid; i < TILE * TILE; i += NTHREADS) {
        int r = i >> 5, c = i & 31;
        int gr = row0 + r, gc = col0 + c;
        if (gr < OH && gc < OW) {
            float mu1 = 0.f, mu2 = 0.f, xx = 0.f, yy = 0.f, xy = 0.f;
            #pragma unroll
            for (int k = 0; k < WIN; ++k) {
                float g = gw.g[k];
                mu1 = fmaf(g, V[0][r][c + k], mu1);
                mu2 = fmaf(g, V[1][r][c + k], mu2);
                xx  = fmaf(g, V[2][r][c + k], xx);
                yy  = fmaf(g, V[3][r][c + k], yy);
                xy  = fmaf(g, V[4][r][c + k], xy);
            }
            float mu1s = mu1 * mu1;
            float mu2s = mu2 * mu2;
            float m12  = mu1 * mu2;
            float s1  = xx - mu1s;
            float s2  = yy - mu2s;
            float s12 = xy - m12;
            float cs   = (2.f * s12 + C2) / (s1 + s2 + C2);
            float ssim = ((2.f * m12 + C1) / (mu1s + mu2s + C1)) * cs;
            sum += ssim;
        }
    }

    // ---- Block reduction ----
    #pragma unroll
    for (int off = 32; off > 0; off >>= 1)
        sum += __shfl_down(sum, off, 64);
    if ((tid & 63) == 0) wsum[tid >> 6] = sum;
    __syncthreads();
    if (tid == 0) {
        float b = 0.f;
        #pragma unroll
        for (int w = 0; w < NTHREADS / 64; ++w) b += wsum[w];
        atomicAdd(accum, (double)b);
    }
}

__global__ void ssim_finalize_kernel(const double* __restrict__ accum,
                                     float* __restrict__ out, double inv_count)
{
    out[0] = (float)(1.0 - accum[0] * inv_count);
}

extern "C" void kernel_launch(void* const* d_in, const int* in_sizes, int n_in,
                              void* d_out, int out_size, void* d_ws, size_t ws_size,
                              hipStream_t stream) {
    const float* X = (const float*)d_in[0];
    const float* Y = (const float*)d_in[1];
    float* out = (float*)d_out;
    double* accum = (double*)d_ws;

    const int N = 16, C = 3, H = 384, W = 512;
    const int NC = N * C;
    const int OH = H - WIN + 1;   // 374
    const int OW = W - WIN + 1;   // 502
    const int tiles_h = (OH + TILE - 1) / TILE;  // 12
    const int tiles_w = (OW + TILE - 1) / TILE;  // 16

    // Gaussian window (computed in double, matches fp32 reference well
    // within the 2e-2 threshold)
    GaussW gw;
    {
        double g[WIN], s = 0.0;
        for (int i = 0; i < WIN; ++i) {
            double d = (double)i - WIN / 2;
            g[i] = exp(-(d * d) / (2.0 * 1.5 * 1.5));
            s += g[i];
        }
        for (int i = 0; i < WIN; ++i) gw.g[i] = (float)(g[i] / s);
    }

    // d_ws is poisoned 0xAA each call — zero the accumulator first.
    hipMemsetAsync(accum, 0, sizeof(double), stream);

    const int nblocks = NC * tiles_h * tiles_w;
    ssim_fused_kernel<<<nblocks, NTHREADS, 0, stream>>>(
        X, Y, accum, gw, H, W, OH, OW, tiles_h, tiles_w);

    const double inv_count = 1.0 / ((double)NC * OH * OW);
    ssim_finalize_kernel<<<1, 1, 0, stream>>>(accum, out, inv_count);
}

// Round 3
// 165.558 us; speedup vs baseline: 1.2931x; 1.2931x over previous
//
#include <hip/hip_runtime.h>
#include <math.h>

#define WIN 11
#define TH 12                       // output rows per band
#define NSTEPS (TH + WIN - 1)       // 22 input rows per band
#define IMG_H 384
#define IMG_W 512
#define OUT_H (IMG_H - WIN + 1)     // 374
#define OUT_W (IMG_W - WIN + 1)     // 502
#define NBANDS 32                   // ceil(374/12)
#define NTHREADS 128                // 128 threads x 4 cols = 512 = full row
#define RBS 524                     // LDS row-buffer stride (floats): 512 + 12 pad

struct GaussW { float g[WIN]; };

// Horizontal 11-tap blur of the 5 channels for this thread's 4 columns,
// plus SSIM epilogue; returns updated running sum.
__device__ __forceinline__ float horiz_ssim(const float (*rbp)[RBS], int c0,
                                            const GaussW& gw, float sum)
{
    const float C1 = 1e-4f, C2 = 9e-4f;
    float res[5][4];
    #pragma unroll
    for (int ch = 0; ch < 5; ++ch) {
        float4 w0 = *(const float4*)&rbp[ch][c0];
        float4 w1 = *(const float4*)&rbp[ch][c0 + 4];
        float4 w2 = *(const float4*)&rbp[ch][c0 + 8];
        float4 w3 = *(const float4*)&rbp[ch][c0 + 12];
        float v[16] = {w0.x, w0.y, w0.z, w0.w, w1.x, w1.y, w1.z, w1.w,
                       w2.x, w2.y, w2.z, w2.w, w3.x, w3.y, w3.z, w3.w};
        float o0 = 0.f, o1 = 0.f, o2 = 0.f, o3 = 0.f;
        #pragma unroll
        for (int k = 0; k < WIN; ++k) {
            float g = gw.g[k];
            o0 = fmaf(g, v[k],     o0);
            o1 = fmaf(g, v[k + 1], o1);
            o2 = fmaf(g, v[k + 2], o2);
            o3 = fmaf(g, v[k + 3], o3);
        }
        res[ch][0] = o0; res[ch][1] = o1; res[ch][2] = o2; res[ch][3] = o3;
    }
    #pragma unroll
    for (int j = 0; j < 4; ++j) {
        if (c0 + j < OUT_W) {
            float mu1 = res[0][j], mu2 = res[1][j];
            float mu1s = mu1 * mu1, mu2s = mu2 * mu2, m12 = mu1 * mu2;
            float s1  = res[2][j] - mu1s;
            float s2  = res[3][j] - mu2s;
            float s12 = res[4][j] - m12;
            float num = fmaf(2.f, m12, C1) * fmaf(2.f, s12, C2);
            float den = (mu1s + mu2s + C1) * (s1 + s2 + C2);
            sum += num * __builtin_amdgcn_rcpf(den);
        }
    }
    return sum;
}

__global__ __launch_bounds__(NTHREADS, 2) void ssim_fused_kernel(
    const float* __restrict__ X, const float* __restrict__ Y,
    double* __restrict__ accum, GaussW gw)
{
    __shared__ float rb[2][5][RBS];
    __shared__ float wsum[2];

    const int img  = blockIdx.x >> 5;   // / NBANDS
    const int band = blockIdx.x & 31;
    const int row0 = band * TH;
    const int t    = threadIdx.x;
    const int c0   = t << 2;            // this thread's 4 columns

    const float* __restrict__ Xb = X + (size_t)img * (IMG_H * IMG_W);
    const float* __restrict__ Yb = Y + (size_t)img * (IMG_H * IMG_W);

    // zero the pad region (cols 512..RBS-1, 12 entries x 10 planes) so the
    // over-read b128 chunks of the last thread see finite values
    if (t < 120) {
        int p  = t / 60;
        int ch = (t % 60) / 12;
        int i  = t % 12;
        rb[p][ch][512 + i] = 0.f;
    }

    float4 wx[WIN], wy[WIN];            // sliding 11-row window in registers
    float sum = 0.f;

    // prime: rows row0 .. row0+9 into wx[1..10] (the first iteration's slide
    // shifts them to wx[0..9] before inserting the 11th row) — wx[0] is
    // write-before-read in that slide, never consumed uninitialized.
    #pragma unroll
    for (int j = 0; j < WIN - 1; ++j) {
        int gr = row0 + j; gr = gr < IMG_H - 1 ? gr : IMG_H - 1;
        wx[j + 1] = *(const float4*)(Xb + (size_t)gr * IMG_W + c0);
        wy[j + 1] = *(const float4*)(Yb + (size_t)gr * IMG_W + c0);
    }

    for (int s = WIN - 1; s < NSTEPS; ++s) {
        // issue loads for input row row0+s (consumed after horizontal pass)
        int gr = row0 + s; gr = gr < IMG_H - 1 ? gr : IMG_H - 1;
        float4 nx = *(const float4*)(Xb + (size_t)gr * IMG_W + c0);
        float4 ny = *(const float4*)(Yb + (size_t)gr * IMG_W + c0);

        // horizontal + epilogue for the V row written at step s-1
        int rr = row0 + s - WIN;        // output row of that V row
        if (s > WIN - 1 && rr < OUT_H)  // uniform condition
            sum = horiz_ssim(rb[(s - 1) & 1], c0, gw, sum);

        // slide the window, insert new row
        #pragma unroll
        for (int j = 0; j < WIN - 1; ++j) { wx[j] = wx[j + 1]; wy[j] = wy[j + 1]; }
        wx[WIN - 1] = nx; wy[WIN - 1] = ny;

        // vertical 11-tap blur of 5 channels for 4 columns -> V row row0+s-10
        float4 m1 = {0,0,0,0}, m2 = {0,0,0,0};
        float4 vxx = {0,0,0,0}, vyy = {0,0,0,0}, vxy = {0,0,0,0};
        #pragma unroll
        for (int k = 0; k < WIN; ++k) {
            float g = gw.g[k];
            float4 a = wx[k], b = wy[k];
            #define SSIM_COMP(f)                                   \
                { m1.f = fmaf(g, a.f, m1.f);                       \
                  m2.f = fmaf(g, b.f, m2.f);                       \
                  float t1 = g * a.f;                              \
                  vxx.f = fmaf(t1, a.f, vxx.f);                    \
                  vxy.f = fmaf(t1, b.f, vxy.f);                    \
                  float t2 = g * b.f;                              \
                  vyy.f = fmaf(t2, b.f, vyy.f); }
            SSIM_COMP(x) SSIM_COMP(y) SSIM_COMP(z) SSIM_COMP(w)
            #undef SSIM_COMP
        }
        const int p = s & 1;
        *(float4*)&rb[p][0][c0] = m1;
        *(float4*)&rb[p][1][c0] = m2;
        *(float4*)&rb[p][2][c0] = vxx;
        *(float4*)&rb[p][3][c0] = vyy;
        *(float4*)&rb[p][4][c0] = vxy;
        __syncthreads();
    }

    // final horizontal: V row row0+TH-1, written at step NSTEPS-1
    {
        int rr = row0 + TH - 1;
        if (rr < OUT_H)
            sum = horiz_ssim(rb[(NSTEPS - 1) & 1], c0, gw, sum);
    }

    // block reduction -> one double atomic per block
    #pragma unroll
    for (int off = 32; off; off >>= 1)
        sum += __shfl_down(sum, off, 64);
    if ((t & 63) == 0) wsum[t >> 6] = sum;
    __syncthreads();
    if (t == 0)
        atomicAdd(accum, (double)(wsum[0] + wsum[1]));
}

__global__ void ssim_finalize_kernel(const double* __restrict__ accum,
                                     float* __restrict__ out, double inv_count)
{
    out[0] = (float)(1.0 - accum[0] * inv_count);
}

extern "C" void kernel_launch(void* const* d_in, const int* in_sizes, int n_in,
                              void* d_out, int out_size, void* d_ws, size_t ws_size,
                              hipStream_t stream) {
    const float* X = (const float*)d_in[0];
    const float* Y = (const float*)d_in[1];
    float* out = (float*)d_out;
    double* accum = (double*)d_ws;

    const int NC = 16 * 3;

    GaussW gw;
    {
        double g[WIN], ssum = 0.0;
        for (int i = 0; i < WIN; ++i) {
            double d = (double)i - WIN / 2;
            g[i] = exp(-(d * d) / (2.0 * 1.5 * 1.5));
            ssum += g[i];
        }
        for (int i = 0; i < WIN; ++i) gw.g[i] = (float)(g[i] / ssum);
    }

    hipMemsetAsync(accum, 0, sizeof(double), stream);

    const int nblocks = NC * NBANDS;   // 48 * 32 = 1536
    ssim_fused_kernel<<<nblocks, NTHREADS, 0, stream>>>(X, Y, accum, gw);

    const double inv_count = 1.0 / ((double)NC * OUT_H * OUT_W);
    ssim_finalize_kernel<<<1, 1, 0, stream>>>(accum, out, inv_count);
}

// Round 4
// 149.325 us; speedup vs baseline: 1.4337x; 1.1087x over previous
//
#include <hip/hip_runtime.h>
#include <math.h>

#define WIN 11
#define IMG_H 384
#define IMG_W 512
#define OUT_H (IMG_H - WIN + 1)   // 374
#define OUT_W (IMG_W - WIN + 1)   // 502
#define ROWS_PER_BLOCK 4
#define NBLK_X ((OUT_H + ROWS_PER_BLOCK - 1) / ROWS_PER_BLOCK)  // 94
#define NBUCKETS 256

struct GaussW { float g[WIN]; };

// Horizontal 11-tap over this lane's 8 columns; halo (10 cols) fetched from
// lanes +1/+2 via wave shuffles — no LDS storage, no barriers, no bank
// conflicts. acc[8] holds the vertically-blurred channel; out[8] receives
// the separably-blurred result.
#define HORIZ_CH(acc, out)                                                  \
    {                                                                       \
        float v[18];                                                        \
        _Pragma("unroll")                                                   \
        for (int j = 0; j < 8; ++j) v[j] = acc[j];                          \
        _Pragma("unroll")                                                   \
        for (int j = 0; j < 8; ++j) v[8 + j] = __shfl(acc[j], lane + 1, 64);\
        v[16] = __shfl(acc[0], lane + 2, 64);                               \
        v[17] = __shfl(acc[1], lane + 2, 64);                               \
        _Pragma("unroll")                                                   \
        for (int j = 0; j < 8; ++j) {                                       \
            float o = 0.f;                                                  \
            _Pragma("unroll")                                               \
            for (int k = 0; k < WIN; ++k) o = fmaf(gw.g[k], v[j + k], o);   \
            out[j] = o;                                                     \
        }                                                                   \
    }

__global__ __launch_bounds__(64 * ROWS_PER_BLOCK) void ssim_fused_kernel(
    const float* __restrict__ X, const float* __restrict__ Y,
    double* __restrict__ accum, GaussW gw)
{
    const int wave = threadIdx.x >> 6;
    const int lane = threadIdx.x & 63;
    const int row  = blockIdx.x * ROWS_PER_BLOCK + wave;  // output row
    const int img  = blockIdx.y;
    if (row >= OUT_H) return;   // no barriers anywhere — early-out is safe

    const int c0 = lane << 3;   // this lane's 8 columns
    const float* __restrict__ px = X + ((size_t)img * IMG_H + row) * IMG_W + c0;
    const float* __restrict__ py = Y + ((size_t)img * IMG_H + row) * IMG_W + c0;

    // ---- vertical 11-tap: stream rows row..row+10 from global (L1/L2) ----
    float m1[8], m2[8], xx[8], yy[8], xy[8];
    #pragma unroll
    for (int j = 0; j < 8; ++j) { m1[j] = m2[j] = xx[j] = yy[j] = xy[j] = 0.f; }

    #pragma unroll
    for (int k = 0; k < WIN; ++k) {
        float4 xa = *(const float4*)(px + k * IMG_W);
        float4 xb = *(const float4*)(px + k * IMG_W + 4);
        float4 ya = *(const float4*)(py + k * IMG_W);
        float4 yb = *(const float4*)(py + k * IMG_W + 4);
        float xs[8] = {xa.x, xa.y, xa.z, xa.w, xb.x, xb.y, xb.z, xb.w};
        float ys[8] = {ya.x, ya.y, ya.z, ya.w, yb.x, yb.y, yb.z, yb.w};
        const float g = gw.g[k];
        #pragma unroll
        for (int j = 0; j < 8; ++j) {
            float x = xs[j], y = ys[j];
            m1[j] = fmaf(g, x, m1[j]);
            m2[j] = fmaf(g, y, m2[j]);
            float t = g * x;
            xx[j] = fmaf(t, x, xx[j]);
            xy[j] = fmaf(t, y, xy[j]);
            float u = g * y;
            yy[j] = fmaf(u, y, yy[j]);
        }
    }

    // ---- horizontal 11-tap via wave shuffles ----
    float h1[8], h2[8], hxx[8], hyy[8], hxy[8];
    HORIZ_CH(m1, h1)
    HORIZ_CH(m2, h2)
    HORIZ_CH(xx, hxx)
    HORIZ_CH(yy, hyy)
    HORIZ_CH(xy, hxy)

    // ---- SSIM epilogue ----
    const float C1 = 1e-4f, C2 = 9e-4f;
    float sum = 0.f;
    #pragma unroll
    for (int j = 0; j < 8; ++j) {
        float mu1 = h1[j], mu2 = h2[j];
        float mu1s = mu1 * mu1, mu2s = mu2 * mu2, m12 = mu1 * mu2;
        float s1  = hxx[j] - mu1s;
        float s2  = hyy[j] - mu2s;
        float s12 = hxy[j] - m12;
        float num = fmaf(2.f, m12, C1) * fmaf(2.f, s12, C2);
        float den = (mu1s + mu2s + C1) * (s1 + s2 + C2);
        float ssim = num * __builtin_amdgcn_rcpf(den);
        sum += (c0 + j < OUT_W) ? ssim : 0.f;
    }

    // ---- wave reduction -> one f64 atomic per wave, bucketed ----
    #pragma unroll
    for (int off = 32; off; off >>= 1)
        sum += __shfl_down(sum, off, 64);
    if (lane == 0) {
        int gwid = (blockIdx.y * NBLK_X + blockIdx.x) * ROWS_PER_BLOCK + wave;
        atomicAdd(&accum[gwid & (NBUCKETS - 1)], (double)sum);
    }
}

__global__ void ssim_finalize_kernel(const double* __restrict__ accum,
                                     float* __restrict__ out, double inv_count)
{
    const int lane = threadIdx.x;
    double s = 0.0;
    for (int i = lane; i < NBUCKETS; i += 64) s += accum[i];
    #pragma unroll
    for (int off = 32; off; off >>= 1)
        s += __shfl_down(s, off, 64);
    if (lane == 0) out[0] = (float)(1.0 - s * inv_count);
}

extern "C" void kernel_launch(void* const* d_in, const int* in_sizes, int n_in,
                              void* d_out, int out_size, void* d_ws, size_t ws_size,
                              hipStream_t stream) {
    const float* X = (const float*)d_in[0];
    const float* Y = (const float*)d_in[1];
    float* out = (float*)d_out;
    double* accum = (double*)d_ws;

    const int NC = 16 * 3;

    GaussW gw;
    {
        double g[WIN], ssum = 0.0;
        for (int i = 0; i < WIN; ++i) {
            double d = (double)i - WIN / 2;
            g[i] = exp(-(d * d) / (2.0 * 1.5 * 1.5));
            ssum += g[i];
        }
        for (int i = 0; i < WIN; ++i) gw.g[i] = (float)(g[i] / ssum);
    }

    // d_ws is re-poisoned 0xAA before every call — zero the buckets.
    hipMemsetAsync(accum, 0, NBUCKETS * sizeof(double), stream);

    dim3 grid(NBLK_X, NC);               // 94 x 48 = 4512 blocks
    ssim_fused_kernel<<<grid, 64 * ROWS_PER_BLOCK, 0, stream>>>(X, Y, accum, gw);

    const double inv_count = 1.0 / ((double)NC * OUT_H * OUT_W);
    ssim_finalize_kernel<<<1, 64, 0, stream>>>(accum, out, inv_count);
}